// Round 9
// baseline (273.768 us; speedup 1.0000x reference)
//
#include <hip/hip_runtime.h>
#include <hip/hip_bf16.h>

// GAT layer: N=100000 nodes, E=1600000 edges, IN=128, H=4 heads x D=32.
// Pipeline:
//   K0 memset:  zero cnt (per-node degree) + ccnt (coarse totals), adjacent.
//   K1 prep_k:  (1 block) W -> bf16 hi/lo table (144 cols x 128 k): cols 0-127
//               = W rows, cols 128-135 = v_l/v_r = W^T a_left/right.
//   K2 fused_k: heterogeneous block roles —
//       role G: h = x @ W^T via MFMA bf16 split-precision (truncated hi + lo),
//               B-frags from prep table, el/er from wave 0's extra col-tile.
//       role A: LDS-staged coarse binning (512-node bins), 2048 edges/block,
//               hist -> one global atomic per (block,bin) -> LDS reorder ->
//               coalesced copy-out to c1buf. Also counts per-node degree via
//               fire-and-forget atomicAdd into cnt[] (L2-resident, 400 KB).
//   K3 binB_k:  per coarse bin (196 x 512): coarse scan -> scan cnt slice ->
//               offsets/cur -> SINGLE pass over c1buf: LDS rank atomic + csr.
//   K4 agg_k:   per dst node (1 wave, lane-quarters; 16-edge main loop = 8
//               gathers in flight), csr preloaded 64-wide + __shfl.

constexpr int IN_DIM = 128;
constexpr int HD     = 128;    // H*D
constexpr int CSHIFT = 9;      // 512 nodes per coarse bin
constexpr int CCAP   = 9216;   // mean 8163 + ~11 sigma
constexpr int CPAD   = 16;     // pad coarse counters to one per 64B line
constexpr int WCOLS  = 144;    // 128 W cols + 8 v cols + 8 pad

typedef float f32x4 __attribute__((ext_vector_type(4)));
typedef short short8 __attribute__((ext_vector_type(8)));   // 8 bf16 = 4 VGPRs

__device__ __forceinline__ unsigned short f2bf(float f) {
  __hip_bfloat16 b = __float2bfloat16(f);   // RNE
  return *(unsigned short*)&b;
}
__device__ __forceinline__ float bfl(unsigned u) { return __uint_as_float(u << 16); }
__device__ __forceinline__ float bfh(unsigned u) { return __uint_as_float(u & 0xffff0000u); }

// ---------------------------------------------------------------------------
// prep: W (+fused attention vectors) -> bf16 hi/lo table.
// hi = bit-truncation (lo captures the remainder to ~2^-16 relative).
// ---------------------------------------------------------------------------
__global__ __launch_bounds__(1024)
void prep_k(const float* __restrict__ W, const float* __restrict__ a_left,
            const float* __restrict__ a_right,
            unsigned short* __restrict__ Whb, unsigned short* __restrict__ Wlb) {
  const int t = threadIdx.x;

  // cols 0..127: straight W rows (out-major), hi/lo split
  for (int i = t; i < 128 * 128; i += 1024) {
    float w = W[i];
    unsigned wu = __float_as_uint(w);
    unsigned short h = (unsigned short)(wu >> 16);
    float hf = __uint_as_float(wu & 0xffff0000u);
    Whb[i] = h;
    Wlb[i] = f2bf(w - hf);
  }
  // cols 128..135: v[vec][k] = sum_d a[vec&3][d] * W[(vec&3)*32+d][k]
  {
    int vec = t >> 7;          // 0..7  (0-3 = left, 4-7 = right)
    int k   = t & 127;
    int hd  = vec & 3;
    const float* av = (vec < 4) ? a_left : a_right;
    float s = 0.f;
    for (int d = 0; d < 32; ++d) s += av[hd * 32 + d] * W[(hd * 32 + d) * IN_DIM + k];
    unsigned su = __float_as_uint(s);
    unsigned short h = (unsigned short)(su >> 16);
    float hf = __uint_as_float(su & 0xffff0000u);
    Whb[(128 + vec) * 128 + k] = h;
    Wlb[(128 + vec) * 128 + k] = f2bf(s - hf);
  }
  // cols 136..143: zero
  for (int i = t; i < 8 * 128; i += 1024) {
    Whb[136 * 128 + i] = 0;
    Wlb[136 * 128 + i] = 0;
  }
}

// ---------------------------------------------------------------------------
// Role G: MFMA gemm (R8-verified). 64 nodes x 128 cols per block; 4 waves = 4
// heads; wave 0 additionally computes the v-tile -> el/er direct.
// ---------------------------------------------------------------------------
__device__ __forceinline__
void gemm_role(char* xs, int gb_idx,
               const float* __restrict__ x,
               const unsigned short* __restrict__ Whb,
               const unsigned short* __restrict__ Wlb,
               unsigned int* __restrict__ hb,
               float* __restrict__ el, float* __restrict__ er, int N) {
  const int tid  = threadIdx.x;
  const int lane = tid & 63;
  const int wv   = tid >> 6;        // wave id == head
  const int lcol = lane & 15;
  const int lk   = lane >> 4;
  const int n0   = gb_idx * 64;

#pragma unroll
  for (int i = 0; i < 8; ++i) {
    int f  = tid + 256 * i;
    int r  = f >> 5;
    int c4 = f & 31;
    int node = n0 + r;
    float4 v = make_float4(0.f, 0.f, 0.f, 0.f);
    if (node < N) v = *(const float4*)&x[(size_t)node * IN_DIM + c4 * 4];
    float vf[4] = {v.x, v.y, v.z, v.w};
    unsigned short hs[4], ls[4];
#pragma unroll
    for (int j = 0; j < 4; ++j) {
      unsigned xu = __float_as_uint(vf[j]);
      hs[j] = (unsigned short)(xu >> 16);                    // truncated hi
      float hf = __uint_as_float(xu & 0xffff0000u);
      ls[j] = f2bf(vf[j] - hf);                              // exact-ish lo
    }
    int sw = (c4 * 8) ^ ((r & 7) << 4);
    uint2 ph = make_uint2((unsigned)hs[0] | ((unsigned)hs[1] << 16),
                          (unsigned)hs[2] | ((unsigned)hs[3] << 16));
    uint2 pl = make_uint2((unsigned)ls[0] | ((unsigned)ls[1] << 16),
                          (unsigned)ls[2] | ((unsigned)ls[3] << 16));
    *(uint2*)&xs[r * 256 + sw]         = ph;
    *(uint2*)&xs[16384 + r * 256 + sw] = pl;
  }
  __syncthreads();

  f32x4 acc[4][2];
  f32x4 acc2[4];
#pragma unroll
  for (int rt = 0; rt < 4; ++rt) {
    acc[rt][0] = (f32x4){0.f, 0.f, 0.f, 0.f};
    acc[rt][1] = (f32x4){0.f, 0.f, 0.f, 0.f};
    acc2[rt]   = (f32x4){0.f, 0.f, 0.f, 0.f};
  }

#pragma unroll
  for (int ks = 0; ks < 4; ++ks) {
    const int kb = ks * 32 + lk * 8;   // element offset within a 128-k row
    short8 bh0 = *(const short8*)&Whb[(size_t)(wv * 32 + lcol) * 128 + kb];
    short8 bl0 = *(const short8*)&Wlb[(size_t)(wv * 32 + lcol) * 128 + kb];
    short8 bh1 = *(const short8*)&Whb[(size_t)(wv * 32 + 16 + lcol) * 128 + kb];
    short8 bl1 = *(const short8*)&Wlb[(size_t)(wv * 32 + 16 + lcol) * 128 + kb];
    short8 bh2 = {}, bl2 = {};
    if (wv == 0) {
      bh2 = *(const short8*)&Whb[(size_t)(128 + lcol) * 128 + kb];
      bl2 = *(const short8*)&Wlb[(size_t)(128 + lcol) * 128 + kb];
    }
#pragma unroll
    for (int rt = 0; rt < 4; ++rt) {
      int row = rt * 16 + lcol;
      int kbyte = ks * 64 + lk * 16;
      int ad  = row * 256 + (kbyte ^ ((row & 7) << 4));
      short8 ah = *(const short8*)&xs[ad];
      short8 al = *(const short8*)&xs[16384 + ad];
      acc[rt][0] = __builtin_amdgcn_mfma_f32_16x16x32_bf16(ah, bh0, acc[rt][0], 0, 0, 0);
      acc[rt][0] = __builtin_amdgcn_mfma_f32_16x16x32_bf16(ah, bl0, acc[rt][0], 0, 0, 0);
      acc[rt][0] = __builtin_amdgcn_mfma_f32_16x16x32_bf16(al, bh0, acc[rt][0], 0, 0, 0);
      acc[rt][1] = __builtin_amdgcn_mfma_f32_16x16x32_bf16(ah, bh1, acc[rt][1], 0, 0, 0);
      acc[rt][1] = __builtin_amdgcn_mfma_f32_16x16x32_bf16(ah, bl1, acc[rt][1], 0, 0, 0);
      acc[rt][1] = __builtin_amdgcn_mfma_f32_16x16x32_bf16(al, bh1, acc[rt][1], 0, 0, 0);
      if (wv == 0) {
        acc2[rt] = __builtin_amdgcn_mfma_f32_16x16x32_bf16(ah, bh2, acc2[rt], 0, 0, 0);
        acc2[rt] = __builtin_amdgcn_mfma_f32_16x16x32_bf16(ah, bl2, acc2[rt], 0, 0, 0);
        acc2[rt] = __builtin_amdgcn_mfma_f32_16x16x32_bf16(al, bh2, acc2[rt], 0, 0, 0);
      }
    }
  }

  // ---- epilogue: hb store (bf16 pairs via 1 shfl); el/er direct from acc2 ----
#pragma unroll
  for (int rt = 0; rt < 4; ++rt) {
#pragma unroll
    for (int ct = 0; ct < 2; ++ct) {
      float av[4] = {acc[rt][ct][0], acc[rt][ct][1], acc[rt][ct][2], acc[rt][ct][3]};
      float pt[4];
#pragma unroll
      for (int r = 0; r < 4; ++r) pt[r] = __shfl_xor(av[r], 1, 64);
      int col = wv * 32 + ct * 16 + lcol;
      int nb  = n0 + rt * 16 + lk * 4;
      if (!(lane & 1)) {
#pragma unroll
        for (int r = 0; r < 4; ++r) {
          int node = nb + r;
          if (node < N)
            hb[(size_t)node * 64 + (col >> 1)] =
                (unsigned)f2bf(av[r]) | ((unsigned)f2bf(pt[r]) << 16);
        }
      }
    }
    if (wv == 0 && lcol < 8) {
      float* dstp = (lcol < 4) ? el : er;
      int hd = lcol & 3;
      int nb = n0 + rt * 16 + lk * 4;
#pragma unroll
      for (int r = 0; r < 4; ++r) {
        int node = nb + r;
        if (node < N) dstp[node * 4 + hd] = acc2[rt][r];
      }
    }
  }
}

// ---------------------------------------------------------------------------
// Role A: LDS-staged coarse binning + per-node degree count (fire-and-forget
// global atomics into L2-resident cnt[]).
// ---------------------------------------------------------------------------
__device__ __forceinline__
void binA_role(char* smem, int ab_idx,
               const int* __restrict__ ei, int* __restrict__ cnt,
               int* __restrict__ ccnt, unsigned* __restrict__ c1buf,
               int E, int ncb) {
  unsigned*       staged = (unsigned*)smem;                    //  8192 B
  unsigned short* sbin   = (unsigned short*)(smem + 8192);     //  4096 B
  int*            hist   = (int*)(smem + 12288);               //  1024 B
  int*            loff   = (int*)(smem + 13312);               //  1024 B
  int*            cur    = (int*)(smem + 14336);               //  1024 B
  int*            gbase  = (int*)(smem + 15360);               //  1024 B
  int*            lws    = (int*)(smem + 16384);               //    16 B
  const int t = threadIdx.x;
  const int base = ab_idx * 2048;

  hist[t] = 0;
  __syncthreads();

  int src[8], dst[8], bin[8];
#pragma unroll
  for (int i = 0; i < 8; ++i) {
    int e = base + t + 256 * i;
    if (e < E) {
      src[i] = __builtin_nontemporal_load(&ei[e]);
      dst[i] = __builtin_nontemporal_load(&ei[E + e]);
      bin[i] = dst[i] >> CSHIFT;
      atomicAdd(&hist[bin[i]], 1);
      atomicAdd(&cnt[dst[i]], 1);                 // no-return, L2-resident
    } else bin[i] = -1;
  }
  __syncthreads();

  int v = hist[t], s = v;
#pragma unroll
  for (int d = 1; d < 64; d <<= 1) {
    int u = __shfl_up(s, d, 64);
    if ((t & 63) >= d) s += u;
  }
  if ((t & 63) == 63) lws[t >> 6] = s;
  __syncthreads();
  int prefix = 0;
  for (int i = 0; i < (t >> 6); ++i) prefix += lws[i];
  int excl = prefix + s - v;
  loff[t] = excl;
  cur[t]  = excl;
  gbase[t] = (t < ncb && v > 0) ? atomicAdd(&ccnt[t * CPAD], v) : 0;
  __syncthreads();

#pragma unroll
  for (int i = 0; i < 8; ++i) {
    if (bin[i] >= 0) {
      int p = atomicAdd(&cur[bin[i]], 1);
      staged[p] = (unsigned)src[i] | ((unsigned)(dst[i] & 511) << 17);
      sbin[p]   = (unsigned short)bin[i];
    }
  }
  __syncthreads();

  const int tot = loff[255] + hist[255];
  for (int j = t; j < tot; j += 256) {
    int b = sbin[j];
    int pos = gbase[b] + (j - loff[b]);
    if (pos < CCAP) c1buf[(size_t)b * CCAP + pos] = staged[j];
  }
}

// Fused heterogeneous kernel. Blocks [0, 2*AB) alternate A (odd) / G (even);
// remaining blocks are G. Requires GB >= AB (1563 >= 782 here).
__global__ __launch_bounds__(256)
void fused_k(const float* __restrict__ x,
             const unsigned short* __restrict__ Whb,
             const unsigned short* __restrict__ Wlb,
             unsigned int* __restrict__ hb, float* __restrict__ el,
             float* __restrict__ er, const int* __restrict__ ei,
             int* __restrict__ cnt, int* __restrict__ ccnt,
             unsigned* __restrict__ c1buf,
             int N, int E, int ncb, int nab) {
  __shared__ __align__(16) char smem[32768];
  const int k = blockIdx.x;
  const int twoA = 2 * nab;
  if (k < twoA && (k & 1)) {
    binA_role(smem, k >> 1, ei, cnt, ccnt, c1buf, E, ncb);
  } else {
    int gidx = (k < twoA) ? (k >> 1) : (k - nab);
    gemm_role(smem, gidx, x, Whb, Wlb, hb, el, er, N);
  }
}

// Per coarse bin (512 nodes, 512 threads): coarse scan -> scan cnt slice ->
// offsets/cur -> SINGLE pass over c1buf (LDS rank atomic + csr write).
// [Structure verified correct in R5.]
__global__ __launch_bounds__(512)
void binB_k(const unsigned* __restrict__ c1buf, const int* __restrict__ ccnt,
            const int* __restrict__ cnt, int* __restrict__ offsets,
            int* __restrict__ csr, int N, int ncb, int E) {
  __shared__ int cur[512];
  __shared__ int wsA[8], wsB[8];
  __shared__ int sgb;
  const int b = blockIdx.x, t = threadIdx.x;
  const int w = t >> 6;

  // coarse scan (first 4 waves) + node-count scan (all 8 waves)
  int cv = 0, cs = 0;
  if (t < 256) {
    cv = (t < ncb) ? ccnt[t * CPAD] : 0;
    cs = cv;
#pragma unroll
    for (int d = 1; d < 64; d <<= 1) {
      int u = __shfl_up(cs, d, 64);
      if ((t & 63) >= d) cs += u;
    }
    if ((t & 63) == 63) wsA[w] = cs;
  }
  int v = cnt[(b << CSHIFT) + t];
  int s = v;
#pragma unroll
  for (int d = 1; d < 64; d <<= 1) {
    int u = __shfl_up(s, d, 64);
    if ((t & 63) >= d) s += u;
  }
  if ((t & 63) == 63) wsB[w] = s;
  if (b == 0 && t == 0) offsets[N] = E;
  __syncthreads();
  if (t < 256) {
    int cpre = 0;
    for (int i = 0; i < w; ++i) cpre += wsA[i];
    if (t == b) sgb = cpre + cs - cv;
  }
  __syncthreads();
  const int gb = sgb;
  int pre = 0;
  for (int i = 0; i < w; ++i) pre += wsB[i];
  int off = gb + pre + s - v;
  int node = (b << CSHIFT) + t;
  if (node < N) offsets[node] = off;
  cur[t] = off;
  __syncthreads();

  int m = ccnt[b * CPAD];
  if (m > CCAP) m = CCAP;
  const unsigned* bp = c1buf + (size_t)b * CCAP;
  for (int i = t; i < m; i += 512) {
    unsigned u = bp[i];
    int r = atomicAdd(&cur[u >> 17], 1);
    csr[r] = (int)(u & 0x1FFFFu);
  }
}

// 1 wave per dst node. 16-edge main loop (4 independent pairs = 8 gathers in
// flight per wave), then 8-edge, then masked tail.
__global__ __launch_bounds__(256)
void agg_k(const char* __restrict__ hbc, const char* __restrict__ elc,
           const float* __restrict__ er, const int* __restrict__ offsets,
           const int* __restrict__ csr, float* __restrict__ out, int N) {
  const int wid  = (blockIdx.x * blockDim.x + threadIdx.x) >> 6;
  const int lane = threadIdx.x & 63;
  if (wid >= N) return;
  const int start = offsets[wid];
  const int end   = offsets[wid + 1];
  const int q    = lane >> 4;
  const int ql   = lane & 15;
  const int head = ql >> 2;
  const unsigned qoff = (unsigned)(ql << 4);
  const unsigned hoff = (unsigned)(head << 2);
  const float erv = er[wid * 4 + head];

  float a0=0.f,a1=0.f,a2=0.f,a3=0.f,a4=0.f,a5=0.f,a6=0.f,a7=0.f,den=0.f;

  for (int base = start; base < end; base += 64) {
    int lim = end - base; if (lim > 64) lim = 64;
    int ce  = base + lane;
    int creg = __builtin_nontemporal_load(&csr[(ce < end) ? ce : (end - 1)]);

    int i = 0;
    // 16-edge main loop: 4 independent pairs, 8 vmem in flight
    for (; i + 16 <= lim; i += 16) {
      int s0 = __shfl(creg, i + q, 64);
      int s1 = __shfl(creg, i + 4 + q, 64);
      int s2 = __shfl(creg, i + 8 + q, 64);
      int s3 = __shfl(creg, i + 12 + q, 64);
      uint4 h0 = *(const uint4*)(hbc + (((unsigned)s0 << 8) + qoff));
      uint4 h1 = *(const uint4*)(hbc + (((unsigned)s1 << 8) + qoff));
      uint4 h2 = *(const uint4*)(hbc + (((unsigned)s2 << 8) + qoff));
      uint4 h3 = *(const uint4*)(hbc + (((unsigned)s3 << 8) + qoff));
      float e0 = *(const float*)(elc + (((unsigned)s0 << 4) + hoff));
      float e1 = *(const float*)(elc + (((unsigned)s1 << 4) + hoff));
      float e2 = *(const float*)(elc + (((unsigned)s2 << 4) + hoff));
      float e3 = *(const float*)(elc + (((unsigned)s3 << 4) + hoff));
      float t0 = e0 + erv; t0 = (t0 > 0.f) ? t0 : 0.2f * t0;
      float t1 = e1 + erv; t1 = (t1 > 0.f) ? t1 : 0.2f * t1;
      float t2 = e2 + erv; t2 = (t2 > 0.f) ? t2 : 0.2f * t2;
      float t3 = e3 + erv; t3 = (t3 > 0.f) ? t3 : 0.2f * t3;
      float w0 = __expf(t0), w1 = __expf(t1), w2 = __expf(t2), w3 = __expf(t3);
      a0 += w0 * bfl(h0.x) + w1 * bfl(h1.x) + w2 * bfl(h2.x) + w3 * bfl(h3.x);
      a1 += w0 * bfh(h0.x) + w1 * bfh(h1.x) + w2 * bfh(h2.x) + w3 * bfh(h3.x);
      a2 += w0 * bfl(h0.y) + w1 * bfl(h1.y) + w2 * bfl(h2.y) + w3 * bfl(h3.y);
      a3 += w0 * bfh(h0.y) + w1 * bfh(h1.y) + w2 * bfh(h2.y) + w3 * bfh(h3.y);
      a4 += w0 * bfl(h0.z) + w1 * bfl(h1.z) + w2 * bfl(h2.z) + w3 * bfl(h3.z);
      a5 += w0 * bfh(h0.z) + w1 * bfh(h1.z) + w2 * bfh(h2.z) + w3 * bfh(h3.z);
      a6 += w0 * bfl(h0.w) + w1 * bfl(h1.w) + w2 * bfl(h2.w) + w3 * bfl(h3.w);
      a7 += w0 * bfh(h0.w) + w1 * bfh(h1.w) + w2 * bfh(h2.w) + w3 * bfh(h3.w);
      den += w0 + w1 + w2 + w3;
    }
    // 8-edge step
    if (i + 8 <= lim) {
      int s0 = __shfl(creg, i + q, 64);
      int s1 = __shfl(creg, i + 4 + q, 64);
      uint4 h0 = *(const uint4*)(hbc + (((unsigned)s0 << 8) + qoff));
      uint4 h1 = *(const uint4*)(hbc + (((unsigned)s1 << 8) + qoff));
      float e0 = *(const float*)(elc + (((unsigned)s0 << 4) + hoff));
      float e1 = *(const float*)(elc + (((unsigned)s1 << 4) + hoff));
      float t0 = e0 + erv; t0 = (t0 > 0.f) ? t0 : 0.2f * t0;
      float t1 = e1 + erv; t1 = (t1 > 0.f) ? t1 : 0.2f * t1;
      float w0 = __expf(t0), w1 = __expf(t1);
      a0 += w0 * bfl(h0.x) + w1 * bfl(h1.x);
      a1 += w0 * bfh(h0.x) + w1 * bfh(h1.x);
      a2 += w0 * bfl(h0.y) + w1 * bfl(h1.y);
      a3 += w0 * bfh(h0.y) + w1 * bfh(h1.y);
      a4 += w0 * bfl(h0.z) + w1 * bfl(h1.z);
      a5 += w0 * bfh(h0.z) + w1 * bfh(h1.z);
      a6 += w0 * bfl(h0.w) + w1 * bfl(h1.w);
      a7 += w0 * bfh(h0.w) + w1 * bfh(h1.w);
      den += w0 + w1;
      i += 8;
    }
    // masked tail (up to 7 edges)
    if (i < lim) {
      int i0 = i + q, i1 = i + 4 + q;
      int s0 = __shfl(creg, (i0 < lim) ? i0 : 0, 64);
      int s1 = __shfl(creg, (i1 < lim) ? i1 : 0, 64);
      uint4 h0 = *(const uint4*)(hbc + (((unsigned)s0 << 8) + qoff));
      uint4 h1 = *(const uint4*)(hbc + (((unsigned)s1 << 8) + qoff));
      float e0 = *(const float*)(elc + (((unsigned)s0 << 4) + hoff));
      float e1 = *(const float*)(elc + (((unsigned)s1 << 4) + hoff));
      float t0 = e0 + erv; t0 = (t0 > 0.f) ? t0 : 0.2f * t0;
      float t1 = e1 + erv; t1 = (t1 > 0.f) ? t1 : 0.2f * t1;
      float w0 = __expf(t0), w1 = __expf(t1);
      if (i0 >= lim) w0 = 0.f;
      if (i1 >= lim) w1 = 0.f;
      a0 += w0 * bfl(h0.x) + w1 * bfl(h1.x);
      a1 += w0 * bfh(h0.x) + w1 * bfh(h1.x);
      a2 += w0 * bfl(h0.y) + w1 * bfl(h1.y);
      a3 += w0 * bfh(h0.y) + w1 * bfh(h1.y);
      a4 += w0 * bfl(h0.z) + w1 * bfl(h1.z);
      a5 += w0 * bfh(h0.z) + w1 * bfh(h1.z);
      a6 += w0 * bfl(h0.w) + w1 * bfl(h1.w);
      a7 += w0 * bfh(h0.w) + w1 * bfh(h1.w);
      den += w0 + w1;
    }
  }

#pragma unroll
  for (int m = 16; m < 64; m <<= 1) {
    a0 += __shfl_xor(a0, m, 64);  a1 += __shfl_xor(a1, m, 64);
    a2 += __shfl_xor(a2, m, 64);  a3 += __shfl_xor(a3, m, 64);
    a4 += __shfl_xor(a4, m, 64);  a5 += __shfl_xor(a5, m, 64);
    a6 += __shfl_xor(a6, m, 64);  a7 += __shfl_xor(a7, m, 64);
    den += __shfl_xor(den, m, 64);
  }
  if (q == 0) {
    float inv = 1.f / (den + 1e-8f);
    f32x4 o0 = {a0 * inv, a1 * inv, a2 * inv, a3 * inv};
    f32x4 o1 = {a4 * inv, a5 * inv, a6 * inv, a7 * inv};
    __builtin_nontemporal_store(o0, (f32x4*)&out[(size_t)wid * HD + 8 * ql]);
    __builtin_nontemporal_store(o1, (f32x4*)&out[(size_t)wid * HD + 8 * ql + 4]);
  }
}

extern "C" void kernel_launch(void* const* d_in, const int* in_sizes, int n_in,
                              void* d_out, int out_size, void* d_ws, size_t ws_size,
                              hipStream_t stream) {
  const float* x       = (const float*)d_in[0];
  const int*   ei      = (const int*)d_in[1];   // int32 (2,E) row-major
  const float* W       = (const float*)d_in[2];
  const float* a_left  = (const float*)d_in[3];
  const float* a_right = (const float*)d_in[4];
  float* out = (float*)d_out;

  const int N = in_sizes[0] / IN_DIM;          // 100000
  const int E = in_sizes[1] / 2;               // 1600000
  const int NCB = (N + (1 << CSHIFT) - 1) >> CSHIFT;   // 196 coarse bins
  const int NPAD = NCB << CSHIFT;              // 100352
  const int GB  = (N + 63) / 64;               // 1563 gemm blocks
  const int AB  = (E + 2047) / 2048;           // 782 binA blocks

  // Workspace layout (~43 MB total); keep 16B alignment for short8/uint4 loads
  char* p = (char*)d_ws;
  unsigned int* hb = (unsigned int*)p; p += (size_t)N * 64 * sizeof(unsigned int); // 25.6 MB
  float* el      = (float*)p; p += (size_t)N * 4 * sizeof(float);        // 1.6 MB
  float* er      = (float*)p; p += (size_t)N * 4 * sizeof(float);        // 1.6 MB
  int*   offsets = (int*)p;   p += (size_t)(N + 4) * sizeof(int);        // 0.4 MB (padded to 16B)
  int*   cnt     = (int*)p;   p += (size_t)NPAD * sizeof(int);           // 0.4 MB (zeroed)
  int*   ccnt    = (int*)p;   p += (size_t)256 * CPAD * sizeof(int);     // 16 KB (zeroed, adjacent)
  unsigned short* Whb = (unsigned short*)p; p += (size_t)WCOLS * 128 * sizeof(unsigned short); // 36.9 KB
  unsigned short* Wlb = (unsigned short*)p; p += (size_t)WCOLS * 128 * sizeof(unsigned short); // 36.9 KB
  int*   csr     = (int*)p;   p += (size_t)E * sizeof(int);              // 6.4 MB
  unsigned* c1buf = (unsigned*)p; p += (size_t)NCB * CCAP * sizeof(unsigned); // 7.2 MB

  // zero cnt + ccnt in one call (adjacent)
  hipMemsetAsync(cnt, 0, ((size_t)NPAD + 256 * CPAD) * sizeof(int), stream);

  prep_k<<<1, 1024, 0, stream>>>(W, a_left, a_right, Whb, Wlb);
  fused_k<<<GB + AB, 256, 0, stream>>>(x, Whb, Wlb, hb, el, er,
                                       ei, cnt, ccnt, c1buf, N, E, NCB, AB);
  binB_k<<<NCB, 512, 0, stream>>>(c1buf, ccnt, cnt, offsets, csr, N, NCB, E);
  agg_k<<<(N + 3) / 4, 256, 0, stream>>>((const char*)hb, (const char*)el, er,
                                         offsets, csr, out, N);
}

// Round 10
// 231.840 us; speedup vs baseline: 1.1808x; 1.1808x over previous
//
#include <hip/hip_runtime.h>
#include <hip/hip_bf16.h>

// GAT layer: N=100000 nodes, E=1600000 edges, IN=128, H=4 heads x D=32.
// Pipeline (R8-verified structure; agg upgraded to 16-edge main loop):
//   K0 prep_k:  (1 block) W -> bf16 hi/lo table (144 cols x 128 k): cols 0-127
//               = W rows, cols 128-135 = v_l/v_r = W^T a_left/right. Zeroes ccnt.
//   K1 fused_k: heterogeneous block roles —
//       role G: h = x @ W^T via MFMA bf16 split-precision (truncated hi + lo),
//               B-frags from prep table, el/er from wave 0's extra col-tile.
//       role A: LDS-staged coarse binning (512-node bins), 2048 edges/block,
//               hist -> one global atomic per (block,bin) -> LDS reorder ->
//               coalesced copy-out to c1buf.  NO per-edge global atomics
//               (R9 proved device-scope atomics serialize at the coherence
//               point beyond the per-XCD L2: +28us, +57MB writes).
//   K2 binB_k:  per coarse bin (196 x 512): coarse scan -> per-node histogram
//               (LDS atomics) -> scan -> offsets -> scatter to csr.
//   K3 agg_k:   per dst node (1 wave, lane-quarters); 16-edge main loop =
//               8 independent gathers in flight; csr preloaded 64-wide.

constexpr int IN_DIM = 128;
constexpr int HD     = 128;    // H*D
constexpr int CSHIFT = 9;      // 512 nodes per coarse bin
constexpr int CCAP   = 9216;   // mean 8163 + ~11 sigma
constexpr int CPAD   = 16;     // pad coarse counters to one per 64B line
constexpr int WCOLS  = 144;    // 128 W cols + 8 v cols + 8 pad

typedef float f32x4 __attribute__((ext_vector_type(4)));
typedef short short8 __attribute__((ext_vector_type(8)));   // 8 bf16 = 4 VGPRs

__device__ __forceinline__ unsigned short f2bf(float f) {
  __hip_bfloat16 b = __float2bfloat16(f);   // RNE
  return *(unsigned short*)&b;
}
__device__ __forceinline__ float bfl(unsigned u) { return __uint_as_float(u << 16); }
__device__ __forceinline__ float bfh(unsigned u) { return __uint_as_float(u & 0xffff0000u); }

// ---------------------------------------------------------------------------
// prep: W (+fused attention vectors) -> bf16 hi/lo table; zero ccnt.
// ---------------------------------------------------------------------------
__global__ __launch_bounds__(1024)
void prep_k(const float* __restrict__ W, const float* __restrict__ a_left,
            const float* __restrict__ a_right,
            unsigned short* __restrict__ Whb, unsigned short* __restrict__ Wlb,
            int* __restrict__ ccnt) {
  const int t = threadIdx.x;
  for (int i = t; i < 256 * CPAD; i += 1024) ccnt[i] = 0;

  for (int i = t; i < 128 * 128; i += 1024) {
    float w = W[i];
    unsigned wu = __float_as_uint(w);
    unsigned short h = (unsigned short)(wu >> 16);
    float hf = __uint_as_float(wu & 0xffff0000u);
    Whb[i] = h;
    Wlb[i] = f2bf(w - hf);
  }
  {
    int vec = t >> 7;          // 0..7  (0-3 = left, 4-7 = right)
    int k   = t & 127;
    int hd  = vec & 3;
    const float* av = (vec < 4) ? a_left : a_right;
    float s = 0.f;
    for (int d = 0; d < 32; ++d) s += av[hd * 32 + d] * W[(hd * 32 + d) * IN_DIM + k];
    unsigned su = __float_as_uint(s);
    unsigned short h = (unsigned short)(su >> 16);
    float hf = __uint_as_float(su & 0xffff0000u);
    Whb[(128 + vec) * 128 + k] = h;
    Wlb[(128 + vec) * 128 + k] = f2bf(s - hf);
  }
  for (int i = t; i < 8 * 128; i += 1024) {
    Whb[136 * 128 + i] = 0;
    Wlb[136 * 128 + i] = 0;
  }
}

// ---------------------------------------------------------------------------
// Role G: MFMA gemm (R8-verified).
// ---------------------------------------------------------------------------
__device__ __forceinline__
void gemm_role(char* xs, int gb_idx,
               const float* __restrict__ x,
               const unsigned short* __restrict__ Whb,
               const unsigned short* __restrict__ Wlb,
               unsigned int* __restrict__ hb,
               float* __restrict__ el, float* __restrict__ er, int N) {
  const int tid  = threadIdx.x;
  const int lane = tid & 63;
  const int wv   = tid >> 6;        // wave id == head
  const int lcol = lane & 15;
  const int lk   = lane >> 4;
  const int n0   = gb_idx * 64;

#pragma unroll
  for (int i = 0; i < 8; ++i) {
    int f  = tid + 256 * i;
    int r  = f >> 5;
    int c4 = f & 31;
    int node = n0 + r;
    float4 v = make_float4(0.f, 0.f, 0.f, 0.f);
    if (node < N) v = *(const float4*)&x[(size_t)node * IN_DIM + c4 * 4];
    float vf[4] = {v.x, v.y, v.z, v.w};
    unsigned short hs[4], ls[4];
#pragma unroll
    for (int j = 0; j < 4; ++j) {
      unsigned xu = __float_as_uint(vf[j]);
      hs[j] = (unsigned short)(xu >> 16);                    // truncated hi
      float hf = __uint_as_float(xu & 0xffff0000u);
      ls[j] = f2bf(vf[j] - hf);                              // exact-ish lo
    }
    int sw = (c4 * 8) ^ ((r & 7) << 4);
    uint2 ph = make_uint2((unsigned)hs[0] | ((unsigned)hs[1] << 16),
                          (unsigned)hs[2] | ((unsigned)hs[3] << 16));
    uint2 pl = make_uint2((unsigned)ls[0] | ((unsigned)ls[1] << 16),
                          (unsigned)ls[2] | ((unsigned)ls[3] << 16));
    *(uint2*)&xs[r * 256 + sw]         = ph;
    *(uint2*)&xs[16384 + r * 256 + sw] = pl;
  }
  __syncthreads();

  f32x4 acc[4][2];
  f32x4 acc2[4];
#pragma unroll
  for (int rt = 0; rt < 4; ++rt) {
    acc[rt][0] = (f32x4){0.f, 0.f, 0.f, 0.f};
    acc[rt][1] = (f32x4){0.f, 0.f, 0.f, 0.f};
    acc2[rt]   = (f32x4){0.f, 0.f, 0.f, 0.f};
  }

#pragma unroll
  for (int ks = 0; ks < 4; ++ks) {
    const int kb = ks * 32 + lk * 8;   // element offset within a 128-k row
    short8 bh0 = *(const short8*)&Whb[(size_t)(wv * 32 + lcol) * 128 + kb];
    short8 bl0 = *(const short8*)&Wlb[(size_t)(wv * 32 + lcol) * 128 + kb];
    short8 bh1 = *(const short8*)&Whb[(size_t)(wv * 32 + 16 + lcol) * 128 + kb];
    short8 bl1 = *(const short8*)&Wlb[(size_t)(wv * 32 + 16 + lcol) * 128 + kb];
    short8 bh2 = {}, bl2 = {};
    if (wv == 0) {
      bh2 = *(const short8*)&Whb[(size_t)(128 + lcol) * 128 + kb];
      bl2 = *(const short8*)&Wlb[(size_t)(128 + lcol) * 128 + kb];
    }
#pragma unroll
    for (int rt = 0; rt < 4; ++rt) {
      int row = rt * 16 + lcol;
      int kbyte = ks * 64 + lk * 16;
      int ad  = row * 256 + (kbyte ^ ((row & 7) << 4));
      short8 ah = *(const short8*)&xs[ad];
      short8 al = *(const short8*)&xs[16384 + ad];
      acc[rt][0] = __builtin_amdgcn_mfma_f32_16x16x32_bf16(ah, bh0, acc[rt][0], 0, 0, 0);
      acc[rt][0] = __builtin_amdgcn_mfma_f32_16x16x32_bf16(ah, bl0, acc[rt][0], 0, 0, 0);
      acc[rt][0] = __builtin_amdgcn_mfma_f32_16x16x32_bf16(al, bh0, acc[rt][0], 0, 0, 0);
      acc[rt][1] = __builtin_amdgcn_mfma_f32_16x16x32_bf16(ah, bh1, acc[rt][1], 0, 0, 0);
      acc[rt][1] = __builtin_amdgcn_mfma_f32_16x16x32_bf16(ah, bl1, acc[rt][1], 0, 0, 0);
      acc[rt][1] = __builtin_amdgcn_mfma_f32_16x16x32_bf16(al, bh1, acc[rt][1], 0, 0, 0);
      if (wv == 0) {
        acc2[rt] = __builtin_amdgcn_mfma_f32_16x16x32_bf16(ah, bh2, acc2[rt], 0, 0, 0);
        acc2[rt] = __builtin_amdgcn_mfma_f32_16x16x32_bf16(ah, bl2, acc2[rt], 0, 0, 0);
        acc2[rt] = __builtin_amdgcn_mfma_f32_16x16x32_bf16(al, bh2, acc2[rt], 0, 0, 0);
      }
    }
  }

#pragma unroll
  for (int rt = 0; rt < 4; ++rt) {
#pragma unroll
    for (int ct = 0; ct < 2; ++ct) {
      float av[4] = {acc[rt][ct][0], acc[rt][ct][1], acc[rt][ct][2], acc[rt][ct][3]};
      float pt[4];
#pragma unroll
      for (int r = 0; r < 4; ++r) pt[r] = __shfl_xor(av[r], 1, 64);
      int col = wv * 32 + ct * 16 + lcol;
      int nb  = n0 + rt * 16 + lk * 4;
      if (!(lane & 1)) {
#pragma unroll
        for (int r = 0; r < 4; ++r) {
          int node = nb + r;
          if (node < N)
            hb[(size_t)node * 64 + (col >> 1)] =
                (unsigned)f2bf(av[r]) | ((unsigned)f2bf(pt[r]) << 16);
        }
      }
    }
    if (wv == 0 && lcol < 8) {
      float* dstp = (lcol < 4) ? el : er;
      int hd = lcol & 3;
      int nb = n0 + rt * 16 + lk * 4;
#pragma unroll
      for (int r = 0; r < 4; ++r) {
        int node = nb + r;
        if (node < N) dstp[node * 4 + hd] = acc2[rt][r];
      }
    }
  }
}

// ---------------------------------------------------------------------------
// Role A: LDS-staged coarse binning (R8-verified; no per-edge global atomics).
// ---------------------------------------------------------------------------
__device__ __forceinline__
void binA_role(char* smem, int ab_idx,
               const int* __restrict__ ei, int* __restrict__ ccnt,
               unsigned* __restrict__ c1buf, int E, int ncb) {
  unsigned*       staged = (unsigned*)smem;                    //  8192 B
  unsigned short* sbin   = (unsigned short*)(smem + 8192);     //  4096 B
  int*            hist   = (int*)(smem + 12288);               //  1024 B
  int*            loff   = (int*)(smem + 13312);               //  1024 B
  int*            cur    = (int*)(smem + 14336);               //  1024 B
  int*            gbase  = (int*)(smem + 15360);               //  1024 B
  int*            lws    = (int*)(smem + 16384);               //    16 B
  const int t = threadIdx.x;
  const int base = ab_idx * 2048;

  hist[t] = 0;
  __syncthreads();

  int src[8], dst[8], bin[8];
#pragma unroll
  for (int i = 0; i < 8; ++i) {
    int e = base + t + 256 * i;
    if (e < E) {
      src[i] = __builtin_nontemporal_load(&ei[e]);
      dst[i] = __builtin_nontemporal_load(&ei[E + e]);
      bin[i] = dst[i] >> CSHIFT;
      atomicAdd(&hist[bin[i]], 1);
    } else bin[i] = -1;
  }
  __syncthreads();

  int v = hist[t], s = v;
#pragma unroll
  for (int d = 1; d < 64; d <<= 1) {
    int u = __shfl_up(s, d, 64);
    if ((t & 63) >= d) s += u;
  }
  if ((t & 63) == 63) lws[t >> 6] = s;
  __syncthreads();
  int prefix = 0;
  for (int i = 0; i < (t >> 6); ++i) prefix += lws[i];
  int excl = prefix + s - v;
  loff[t] = excl;
  cur[t]  = excl;
  gbase[t] = (t < ncb && v > 0) ? atomicAdd(&ccnt[t * CPAD], v) : 0;
  __syncthreads();

#pragma unroll
  for (int i = 0; i < 8; ++i) {
    if (bin[i] >= 0) {
      int p = atomicAdd(&cur[bin[i]], 1);
      staged[p] = (unsigned)src[i] | ((unsigned)(dst[i] & 511) << 17);
      sbin[p]   = (unsigned short)bin[i];
    }
  }
  __syncthreads();

  const int tot = loff[255] + hist[255];
  for (int j = t; j < tot; j += 256) {
    int b = sbin[j];
    int pos = gbase[b] + (j - loff[b]);
    if (pos < CCAP) c1buf[(size_t)b * CCAP + pos] = staged[j];
  }
}

// Fused heterogeneous kernel. Blocks [0, 2*AB) alternate A (odd) / G (even);
// remaining blocks are G. Requires GB >= AB (1563 >= 782 here).
__global__ __launch_bounds__(256)
void fused_k(const float* __restrict__ x,
             const unsigned short* __restrict__ Whb,
             const unsigned short* __restrict__ Wlb,
             unsigned int* __restrict__ hb, float* __restrict__ el,
             float* __restrict__ er, const int* __restrict__ ei,
             int* __restrict__ ccnt, unsigned* __restrict__ c1buf,
             int N, int E, int ncb, int nab) {
  __shared__ __align__(16) char smem[32768];
  const int k = blockIdx.x;
  const int twoA = 2 * nab;
  if (k < twoA && (k & 1)) {
    binA_role(smem, k >> 1, ei, ccnt, c1buf, E, ncb);
  } else {
    int gidx = (k < twoA) ? (k >> 1) : (k - nab);
    gemm_role(smem, gidx, x, Whb, Wlb, hb, el, er, N);
  }
}

// Per coarse bin (512 nodes, 512 threads): coarse scan -> per-node histogram
// (LDS atomics) -> scan -> offsets -> scatter to csr. (R8-verified.)
__global__ __launch_bounds__(512)
void binB_k(const unsigned* __restrict__ c1buf, const int* __restrict__ ccnt,
            int* __restrict__ offsets, int* __restrict__ csr,
            int N, int ncb, int E) {
  __shared__ int hist[512];
  __shared__ int wsum[8];
  __shared__ int lws2[4];
  __shared__ int sgb;
  const int b = blockIdx.x, t = threadIdx.x;

  hist[t] = 0;

  int cv = 0, cs = 0;
  if (t < 256) {
    cv = (t < ncb) ? ccnt[t * CPAD] : 0;
    cs = cv;
#pragma unroll
    for (int d = 1; d < 64; d <<= 1) {
      int u = __shfl_up(cs, d, 64);
      if ((t & 63) >= d) cs += u;
    }
    if ((t & 63) == 63) lws2[t >> 6] = cs;
  }
  if (t == 0 && b == 0) offsets[N] = E;
  __syncthreads();
  if (t < 256) {
    int cpre = 0;
    for (int i = 0; i < (t >> 6); ++i) cpre += lws2[i];
    if (t == b) sgb = cpre + cs - cv;
  }
  __syncthreads();
  const int gb = sgb;

  int m = ccnt[b * CPAD];
  if (m > CCAP) m = CCAP;
  const unsigned* bp = c1buf + (size_t)b * CCAP;
  for (int i = t; i < m; i += 512) atomicAdd(&hist[bp[i] >> 17], 1);
  __syncthreads();

  int v = hist[t], s = v;
#pragma unroll
  for (int d = 1; d < 64; d <<= 1) {
    int u = __shfl_up(s, d, 64);
    if ((t & 63) >= d) s += u;
  }
  if ((t & 63) == 63) wsum[t >> 6] = s;
  __syncthreads();
  int prefix = 0;
  for (int w = 0; w < (t >> 6); ++w) prefix += wsum[w];
  int excl = prefix + s - v;
  int node = (b << CSHIFT) + t;
  if (node < N) offsets[node] = gb + excl;
  hist[t] = excl;
  __syncthreads();

  for (int i = t; i < m; i += 512) {
    unsigned u = bp[i];
    int r = atomicAdd(&hist[u >> 17], 1);
    csr[gb + r] = (int)(u & 0x1FFFFu);
  }
}

// 1 wave per dst node. 16-edge main loop (4 independent pairs = 8 gathers in
// flight per wave), then 8-edge, then masked tail.
__global__ __launch_bounds__(256)
void agg_k(const char* __restrict__ hbc, const char* __restrict__ elc,
           const float* __restrict__ er, const int* __restrict__ offsets,
           const int* __restrict__ csr, float* __restrict__ out, int N) {
  const int wid  = (blockIdx.x * blockDim.x + threadIdx.x) >> 6;
  const int lane = threadIdx.x & 63;
  if (wid >= N) return;
  const int start = offsets[wid];
  const int end   = offsets[wid + 1];
  const int q    = lane >> 4;
  const int ql   = lane & 15;
  const int head = ql >> 2;
  const unsigned qoff = (unsigned)(ql << 4);
  const unsigned hoff = (unsigned)(head << 2);
  const float erv = er[wid * 4 + head];

  float a0=0.f,a1=0.f,a2=0.f,a3=0.f,a4=0.f,a5=0.f,a6=0.f,a7=0.f,den=0.f;

  for (int base = start; base < end; base += 64) {
    int lim = end - base; if (lim > 64) lim = 64;
    int ce  = base + lane;
    int creg = __builtin_nontemporal_load(&csr[(ce < end) ? ce : (end - 1)]);

    int i = 0;
    // 16-edge main loop: 4 independent pairs, 8 vmem in flight
    for (; i + 16 <= lim; i += 16) {
      int s0 = __shfl(creg, i + q, 64);
      int s1 = __shfl(creg, i + 4 + q, 64);
      int s2 = __shfl(creg, i + 8 + q, 64);
      int s3 = __shfl(creg, i + 12 + q, 64);
      uint4 h0 = *(const uint4*)(hbc + (((unsigned)s0 << 8) + qoff));
      uint4 h1 = *(const uint4*)(hbc + (((unsigned)s1 << 8) + qoff));
      uint4 h2 = *(const uint4*)(hbc + (((unsigned)s2 << 8) + qoff));
      uint4 h3 = *(const uint4*)(hbc + (((unsigned)s3 << 8) + qoff));
      float e0 = *(const float*)(elc + (((unsigned)s0 << 4) + hoff));
      float e1 = *(const float*)(elc + (((unsigned)s1 << 4) + hoff));
      float e2 = *(const float*)(elc + (((unsigned)s2 << 4) + hoff));
      float e3 = *(const float*)(elc + (((unsigned)s3 << 4) + hoff));
      float t0 = e0 + erv; t0 = (t0 > 0.f) ? t0 : 0.2f * t0;
      float t1 = e1 + erv; t1 = (t1 > 0.f) ? t1 : 0.2f * t1;
      float t2 = e2 + erv; t2 = (t2 > 0.f) ? t2 : 0.2f * t2;
      float t3 = e3 + erv; t3 = (t3 > 0.f) ? t3 : 0.2f * t3;
      float w0 = __expf(t0), w1 = __expf(t1), w2 = __expf(t2), w3 = __expf(t3);
      a0 += w0 * bfl(h0.x) + w1 * bfl(h1.x) + w2 * bfl(h2.x) + w3 * bfl(h3.x);
      a1 += w0 * bfh(h0.x) + w1 * bfh(h1.x) + w2 * bfh(h2.x) + w3 * bfh(h3.x);
      a2 += w0 * bfl(h0.y) + w1 * bfl(h1.y) + w2 * bfl(h2.y) + w3 * bfl(h3.y);
      a3 += w0 * bfh(h0.y) + w1 * bfh(h1.y) + w2 * bfh(h2.y) + w3 * bfh(h3.y);
      a4 += w0 * bfl(h0.z) + w1 * bfl(h1.z) + w2 * bfl(h2.z) + w3 * bfl(h3.z);
      a5 += w0 * bfh(h0.z) + w1 * bfh(h1.z) + w2 * bfh(h2.z) + w3 * bfh(h3.z);
      a6 += w0 * bfl(h0.w) + w1 * bfl(h1.w) + w2 * bfl(h2.w) + w3 * bfl(h3.w);
      a7 += w0 * bfh(h0.w) + w1 * bfh(h1.w) + w2 * bfh(h2.w) + w3 * bfh(h3.w);
      den += w0 + w1 + w2 + w3;
    }
    // 8-edge step
    if (i + 8 <= lim) {
      int s0 = __shfl(creg, i + q, 64);
      int s1 = __shfl(creg, i + 4 + q, 64);
      uint4 h0 = *(const uint4*)(hbc + (((unsigned)s0 << 8) + qoff));
      uint4 h1 = *(const uint4*)(hbc + (((unsigned)s1 << 8) + qoff));
      float e0 = *(const float*)(elc + (((unsigned)s0 << 4) + hoff));
      float e1 = *(const float*)(elc + (((unsigned)s1 << 4) + hoff));
      float t0 = e0 + erv; t0 = (t0 > 0.f) ? t0 : 0.2f * t0;
      float t1 = e1 + erv; t1 = (t1 > 0.f) ? t1 : 0.2f * t1;
      float w0 = __expf(t0), w1 = __expf(t1);
      a0 += w0 * bfl(h0.x) + w1 * bfl(h1.x);
      a1 += w0 * bfh(h0.x) + w1 * bfh(h1.x);
      a2 += w0 * bfl(h0.y) + w1 * bfl(h1.y);
      a3 += w0 * bfh(h0.y) + w1 * bfh(h1.y);
      a4 += w0 * bfl(h0.z) + w1 * bfl(h1.z);
      a5 += w0 * bfh(h0.z) + w1 * bfh(h1.z);
      a6 += w0 * bfl(h0.w) + w1 * bfl(h1.w);
      a7 += w0 * bfh(h0.w) + w1 * bfh(h1.w);
      den += w0 + w1;
      i += 8;
    }
    // masked tail (up to 7 edges)
    if (i < lim) {
      int i0 = i + q, i1 = i + 4 + q;
      int s0 = __shfl(creg, (i0 < lim) ? i0 : 0, 64);
      int s1 = __shfl(creg, (i1 < lim) ? i1 : 0, 64);
      uint4 h0 = *(const uint4*)(hbc + (((unsigned)s0 << 8) + qoff));
      uint4 h1 = *(const uint4*)(hbc + (((unsigned)s1 << 8) + qoff));
      float e0 = *(const float*)(elc + (((unsigned)s0 << 4) + hoff));
      float e1 = *(const float*)(elc + (((unsigned)s1 << 4) + hoff));
      float t0 = e0 + erv; t0 = (t0 > 0.f) ? t0 : 0.2f * t0;
      float t1 = e1 + erv; t1 = (t1 > 0.f) ? t1 : 0.2f * t1;
      float w0 = __expf(t0), w1 = __expf(t1);
      if (i0 >= lim) w0 = 0.f;
      if (i1 >= lim) w1 = 0.f;
      a0 += w0 * bfl(h0.x) + w1 * bfl(h1.x);
      a1 += w0 * bfh(h0.x) + w1 * bfh(h1.x);
      a2 += w0 * bfl(h0.y) + w1 * bfl(h1.y);
      a3 += w0 * bfh(h0.y) + w1 * bfh(h1.y);
      a4 += w0 * bfl(h0.z) + w1 * bfl(h1.z);
      a5 += w0 * bfh(h0.z) + w1 * bfh(h1.z);
      a6 += w0 * bfl(h0.w) + w1 * bfl(h1.w);
      a7 += w0 * bfh(h0.w) + w1 * bfh(h1.w);
      den += w0 + w1;
    }
  }

#pragma unroll
  for (int m = 16; m < 64; m <<= 1) {
    a0 += __shfl_xor(a0, m, 64);  a1 += __shfl_xor(a1, m, 64);
    a2 += __shfl_xor(a2, m, 64);  a3 += __shfl_xor(a3, m, 64);
    a4 += __shfl_xor(a4, m, 64);  a5 += __shfl_xor(a5, m, 64);
    a6 += __shfl_xor(a6, m, 64);  a7 += __shfl_xor(a7, m, 64);
    den += __shfl_xor(den, m, 64);
  }
  if (q == 0) {
    float inv = 1.f / (den + 1e-8f);
    f32x4 o0 = {a0 * inv, a1 * inv, a2 * inv, a3 * inv};
    f32x4 o1 = {a4 * inv, a5 * inv, a6 * inv, a7 * inv};
    __builtin_nontemporal_store(o0, (f32x4*)&out[(size_t)wid * HD + 8 * ql]);
    __builtin_nontemporal_store(o1, (f32x4*)&out[(size_t)wid * HD + 8 * ql + 4]);
  }
}

extern "C" void kernel_launch(void* const* d_in, const int* in_sizes, int n_in,
                              void* d_out, int out_size, void* d_ws, size_t ws_size,
                              hipStream_t stream) {
  const float* x       = (const float*)d_in[0];
  const int*   ei      = (const int*)d_in[1];   // int32 (2,E) row-major
  const float* W       = (const float*)d_in[2];
  const float* a_left  = (const float*)d_in[3];
  const float* a_right = (const float*)d_in[4];
  float* out = (float*)d_out;

  const int N = in_sizes[0] / IN_DIM;          // 100000
  const int E = in_sizes[1] / 2;               // 1600000
  const int NCB = (N + (1 << CSHIFT) - 1) >> CSHIFT;   // 196 coarse bins
  const int GB  = (N + 63) / 64;               // 1563 gemm blocks
  const int AB  = (E + 2047) / 2048;           // 782 binA blocks

  // Workspace layout (~43 MB total); keep 16B alignment for short8/uint4 loads
  char* p = (char*)d_ws;
  unsigned int* hb = (unsigned int*)p; p += (size_t)N * 64 * sizeof(unsigned int); // 25.6 MB
  float* el      = (float*)p; p += (size_t)N * 4 * sizeof(float);        // 1.6 MB
  float* er      = (float*)p; p += (size_t)N * 4 * sizeof(float);        // 1.6 MB
  int*   offsets = (int*)p;   p += (size_t)(N + 4) * sizeof(int);        // 0.4 MB (padded to 16B)
  int*   ccnt    = (int*)p;   p += (size_t)256 * CPAD * sizeof(int);     // 16 KB
  unsigned short* Whb = (unsigned short*)p; p += (size_t)WCOLS * 128 * sizeof(unsigned short); // 36.9 KB
  unsigned short* Wlb = (unsigned short*)p; p += (size_t)WCOLS * 128 * sizeof(unsigned short); // 36.9 KB
  int*   csr     = (int*)p;   p += (size_t)E * sizeof(int);              // 6.4 MB
  unsigned* c1buf = (unsigned*)p; p += (size_t)NCB * CCAP * sizeof(unsigned); // 7.2 MB

  prep_k<<<1, 1024, 0, stream>>>(W, a_left, a_right, Whb, Wlb, ccnt);
  fused_k<<<GB + AB, 256, 0, stream>>>(x, Whb, Wlb, hb, el, er,
                                       ei, ccnt, c1buf, N, E, NCB, AB);
  binB_k<<<NCB, 512, 0, stream>>>(c1buf, ccnt, offsets, csr, N, NCB, E);
  agg_k<<<(N + 3) / 4, 256, 0, stream>>>((const char*)hb, (const char*)el, er,
                                         offsets, csr, out, N);
}